// Round 3
// baseline (78.992 us; speedup 1.0000x reference)
//
#include <hip/hip_runtime.h>

#define H 256
#define SEQ 2048
#define NBATCH 64
#define M_TOTAL (NBATCH * SEQ)   // 131072 rows
#define BM 64                    // rows per block

using bf16x8 = __attribute__((ext_vector_type(8))) short;
using u16x4  = __attribute__((ext_vector_type(4))) unsigned short;
using f32x4  = __attribute__((ext_vector_type(4))) float;

__device__ __forceinline__ unsigned short f2bf(float x) {
    union { float f; unsigned u; } v; v.f = x;
    unsigned r = v.u + 0x7fffu + ((v.u >> 16) & 1u);   // RNE
    return (unsigned short)(r >> 16);
}
__device__ __forceinline__ float bf2f(unsigned short b) {
    union { unsigned u; float f; } v; v.u = ((unsigned)b) << 16;
    return v.f;
}

// ---------------- prep 1: qpb[d] = sum_c q[c]*W2[c,d] + b1[d] + b2[d] ----------------
__global__ __launch_bounds__(256) void prep_qpb(const float* __restrict__ q,
                                                const float* __restrict__ W2,
                                                const float* __restrict__ b1,
                                                const float* __restrict__ b2,
                                                float* __restrict__ qpb) {
    int t = threadIdx.x;
    float s = 0.f;
#pragma unroll 8
    for (int c = 0; c < H; ++c) s = fmaf(q[c], W2[c * H + t], s);
    qpb[t] = s + b1[t] + b2[t];
}

// ---------------- prep 2: pack W1 into bf16 hi/lo MFMA B-fragment order --------------
// Layout (bf16x8-granules): frag(ct 0..15, ks 0..7, h 0..1)[lane 0..63]:
//   element j: W1split[h][k = ks*32 + (lane>>4)*8 + j][n = ct*16 + (lane&15)]
__global__ __launch_bounds__(256) void prep_bpack(const float* __restrict__ W1,
                                                  unsigned short* __restrict__ Bpack) {
    int tid = blockIdx.x * 256 + threadIdx.x;  // 0..8191 = (ct,ks,lane)
    int ct = tid >> 9;
    int ks = (tid >> 6) & 7;
    int l  = tid & 63;
    bf16x8 hi, lo;
#pragma unroll
    for (int j = 0; j < 8; ++j) {
        int kk = ks * 32 + ((l >> 4) & 3) * 8 + j;
        int nn = ct * 16 + (l & 15);
        float w = W1[kk * H + nn];
        unsigned short h = f2bf(w);
        float rem = w - bf2f(h);
        hi[j] = (short)h;
        lo[j] = (short)f2bf(rem);
    }
    bf16x8* out = (bf16x8*)Bpack;
    out[((ct * 8 + ks) * 2 + 0) * 64 + l] = hi;
    out[((ct * 8 + ks) * 2 + 1) * 64 + l] = lo;
}

// ---------------- main: scores[m] = sum_d tanh(k@W1 + qpb)[m,d] * V[d] ----------------
// 512 threads = 8 waves; each wave owns 64 rows x 32 cols (rt=4, ct=2).
// Explicit SW pipeline: B (L2) double-buffered in regs, issued one ks ahead;
// A ds_reads rotated per-rt right after their consuming MFMAs issue.
__global__ __launch_bounds__(512, 4) void fused_main(const float* __restrict__ kin,
                                                     const unsigned short* __restrict__ Bpack,
                                                     const float* __restrict__ qpb,
                                                     const float* __restrict__ Vp,
                                                     float* __restrict__ out_scores) {
    // LDS: A_hi [64 rows][256 k] bf16 (32 KB) + A_lo (32 KB), XOR-swizzled
    __shared__ __align__(16) unsigned char lds[65536];
    unsigned char* Ahi = lds;
    unsigned char* Alo = lds + 32768;

    const int t  = threadIdx.x;          // 0..511
    const int m0 = blockIdx.x * BM;

    // ---- stage k tile: f32 -> bf16 hi/lo into LDS (128B global per thread) ----
#pragma unroll
    for (int i = 0; i < 8; ++i) {
        int flat = i * 2048 + t * 4;      // covers [64][256] floats
        int r = flat >> 8;
        int c = flat & 255;
        const float4 v = *(const float4*)(kin + (m0 + r) * H + c);
        unsigned short h0 = f2bf(v.x), h1 = f2bf(v.y), h2 = f2bf(v.z), h3 = f2bf(v.w);
        u16x4 hi = {h0, h1, h2, h3};
        u16x4 lo = {f2bf(v.x - bf2f(h0)), f2bf(v.y - bf2f(h1)),
                    f2bf(v.z - bf2f(h2)), f2bf(v.w - bf2f(h3))};
        int addr = (r * 512 + c * 2) ^ ((r & 7) << 4);
        *(u16x4*)(Ahi + addr) = hi;
        *(u16x4*)(Alo + addr) = lo;
    }
    __syncthreads();

    const int wave = t >> 6;             // 0..7
    const int lane = t & 63;
    const int lhi  = lane >> 4;          // 0..3
    const int llo  = lane & 15;          // 0..15

    f32x4 acc[4][2];   // [rt][ct]
#pragma unroll
    for (int a = 0; a < 4; ++a)
#pragma unroll
        for (int b = 0; b < 2; ++b) acc[a][b] = (f32x4){0.f, 0.f, 0.f, 0.f};

    // This wave's B base: granule index (wave*2*8*2)*64 + lane; granule = bf16x8 (16B)
    const bf16x8* BpW = (const bf16x8*)Bpack + (wave * 32) * 64 + lane;
    // offset for (ct,ks,h): ((ct*8+ks)*2+h)*64 granules

    bf16x8 bh[2][2], bl[2][2];   // [buf][ct]
    bf16x8 ah[4], al[4];         // single-buffered, rotated per-rt

    // ---- prologue: load B(ks=0) and A(ks=0) ----
#pragma unroll
    for (int ct = 0; ct < 2; ++ct) {
        bh[0][ct] = BpW[((ct * 8 + 0) * 2 + 0) * 64];
        bl[0][ct] = BpW[((ct * 8 + 0) * 2 + 1) * 64];
    }
#pragma unroll
    for (int rt = 0; rt < 4; ++rt) {
        int r = rt * 16 + llo;
        int byte = (r * 512 + lhi * 16) ^ ((r & 7) << 4);
        ah[rt] = *(const bf16x8*)(Ahi + byte);
        al[rt] = *(const bf16x8*)(Alo + byte);
    }

#pragma unroll
    for (int ks = 0; ks < 8; ++ks) {
        const int cur = ks & 1;
        const int nxt = cur ^ 1;
        // issue next-ks B loads (L2) before this ks's MFMAs: latency hides under MFMA
        if (ks < 7) {
#pragma unroll
            for (int ct = 0; ct < 2; ++ct) {
                bh[nxt][ct] = BpW[((ct * 8 + (ks + 1)) * 2 + 0) * 64];
                bl[nxt][ct] = BpW[((ct * 8 + (ks + 1)) * 2 + 1) * 64];
            }
        }
#pragma unroll
        for (int rt = 0; rt < 4; ++rt) {
            // 6 MFMAs consuming ah[rt]/al[rt] (+ bh/bl[cur])
#pragma unroll
            for (int ct = 0; ct < 2; ++ct) {
                acc[rt][ct] = __builtin_amdgcn_mfma_f32_16x16x32_bf16(ah[rt], bh[cur][ct], acc[rt][ct], 0, 0, 0);
                acc[rt][ct] = __builtin_amdgcn_mfma_f32_16x16x32_bf16(ah[rt], bl[cur][ct], acc[rt][ct], 0, 0, 0);
                acc[rt][ct] = __builtin_amdgcn_mfma_f32_16x16x32_bf16(al[rt], bh[cur][ct], acc[rt][ct], 0, 0, 0);
            }
            // rotate: refill ah[rt]/al[rt] with next ks's fragment (WAR after issue)
            if (ks < 7) {
                int r = rt * 16 + llo;
                int byte = (r * 512 + (ks + 1) * 64 + lhi * 16) ^ ((r & 7) << 4);
                ah[rt] = *(const bf16x8*)(Ahi + byte);
                al[rt] = *(const bf16x8*)(Alo + byte);
            }
        }
    }

    // ---- epilogue: tanh, *V, reduce over this wave's 32 cols ----
    float s[4][4];
#pragma unroll
    for (int a = 0; a < 4; ++a)
#pragma unroll
        for (int b = 0; b < 4; ++b) s[a][b] = 0.f;

#pragma unroll
    for (int ct = 0; ct < 2; ++ct) {
        int n = wave * 32 + ct * 16 + llo;   // global col (C-frag col = lane&15)
        float qv = qpb[n];
        float vv = Vp[n];
#pragma unroll
        for (int rt = 0; rt < 4; ++rt)
#pragma unroll
            for (int i = 0; i < 4; ++i) {
                float x = acc[rt][ct][i] + qv;
                float e = __expf(2.f * x);
                float th = 1.f - 2.f * __builtin_amdgcn_rcpf(e + 1.f);
                s[rt][i] += th * vv;
            }
    }
    // reduce across the 16 column-lanes of each group
#pragma unroll
    for (int rt = 0; rt < 4; ++rt)
#pragma unroll
        for (int i = 0; i < 4; ++i) {
            float r = s[rt][i];
#pragma unroll
            for (int mask = 1; mask < 16; mask <<= 1) r += __shfl_xor(r, mask, 16);
            s[rt][i] = r;   // sum over this wave's 32 cols, row rt*16+lhi*4+i
        }

    __syncthreads();                 // done with A region; reuse as partial buffer
    float* part = (float*)lds;       // [8 waves][64 rows]
    if (llo == 0) {
#pragma unroll
        for (int rt = 0; rt < 4; ++rt)
#pragma unroll
            for (int i = 0; i < 4; ++i)
                part[wave * 64 + rt * 16 + lhi * 4 + i] = s[rt][i];
    }
    __syncthreads();
    if (t < BM) {
        float r = 0.f;
#pragma unroll
        for (int w = 0; w < 8; ++w) r += part[w * 64 + t];
        out_scores[m0 + t] = r;
    }
}

// ---------------- softmax over seq axis, in-place on d_out ----------------
__global__ __launch_bounds__(256) void softmax_kernel(float* __restrict__ out) {
    const int b = blockIdx.x;
    const int t = threadIdx.x;
    float* row = out + b * SEQ;
    float v[8];
#pragma unroll
    for (int j = 0; j < 8; ++j) v[j] = row[t + j * 256];
    float mx = v[0];
#pragma unroll
    for (int j = 1; j < 8; ++j) mx = fmaxf(mx, v[j]);
#pragma unroll
    for (int off = 1; off < 64; off <<= 1) mx = fmaxf(mx, __shfl_xor(mx, off, 64));
    __shared__ float redm[4], reds[4];
    int lane = t & 63, w = t >> 6;
    if (lane == 0) redm[w] = mx;
    __syncthreads();
    mx = fmaxf(fmaxf(redm[0], redm[1]), fmaxf(redm[2], redm[3]));
    float e[8], sum = 0.f;
#pragma unroll
    for (int j = 0; j < 8; ++j) { e[j] = __expf(v[j] - mx); sum += e[j]; }
#pragma unroll
    for (int off = 1; off < 64; off <<= 1) sum += __shfl_xor(sum, off, 64);
    if (lane == 0) reds[w] = sum;
    __syncthreads();
    float inv = 1.0f / (reds[0] + reds[1] + reds[2] + reds[3]);
#pragma unroll
    for (int j = 0; j < 8; ++j) row[t + j * 256] = e[j] * inv;
}

extern "C" void kernel_launch(void* const* d_in, const int* in_sizes, int n_in,
                              void* d_out, int out_size, void* d_ws, size_t ws_size,
                              hipStream_t stream) {
    const float* q  = (const float*)d_in[0];
    const float* k  = (const float*)d_in[1];
    const float* W1 = (const float*)d_in[2];
    const float* b1 = (const float*)d_in[3];
    const float* W2 = (const float*)d_in[4];
    const float* b2 = (const float*)d_in[5];
    const float* V  = (const float*)d_in[6];
    // d_in[7] = bv: scalar added to every score -> softmax-invariant, skipped.
    float* out = (float*)d_out;

    float* qpb = (float*)d_ws;                                     // 1 KB
    unsigned short* Bpack = (unsigned short*)((char*)d_ws + 1024); // 256 KB

    prep_qpb<<<1, 256, 0, stream>>>(q, W2, b1, b2, qpb);
    prep_bpack<<<32, 256, 0, stream>>>(W1, Bpack);
    fused_main<<<M_TOTAL / BM, 512, 0, stream>>>(k, Bpack, qpb, V, out);
    softmax_kernel<<<NBATCH, 256, 0, stream>>>(out);
}

// Round 4
// 77.520 us; speedup vs baseline: 1.0190x; 1.0190x over previous
//
#include <hip/hip_runtime.h>

#define H 256
#define SEQ 2048
#define NBATCH 64
#define M_TOTAL (NBATCH * SEQ)   // 131072 rows
#define BM 64                    // rows per block

using bf16x8 = __attribute__((ext_vector_type(8))) short;
using u16x4  = __attribute__((ext_vector_type(4))) unsigned short;
using f32x4  = __attribute__((ext_vector_type(4))) float;

__device__ __forceinline__ unsigned short f2bf(float x) {
    union { float f; unsigned u; } v; v.f = x;
    unsigned r = v.u + 0x7fffu + ((v.u >> 16) & 1u);   // RNE
    return (unsigned short)(r >> 16);
}
__device__ __forceinline__ float bf2f(unsigned short b) {
    union { unsigned u; float f; } v; v.u = ((unsigned)b) << 16;
    return v.f;
}

// Raw 16B global load pinned in registers: compiler cannot sink/collapse this.
__device__ __forceinline__ bf16x8 gload16(const void* p) {
    bf16x8 r;
    asm volatile("global_load_dwordx4 %0, %1, off" : "=v"(r) : "v"(p));
    return r;
}

// ---------------- prep 1: qpb[d] = sum_c q[c]*W2[c,d] + b1[d] + b2[d] ----------------
__global__ __launch_bounds__(256) void prep_qpb(const float* __restrict__ q,
                                                const float* __restrict__ W2,
                                                const float* __restrict__ b1,
                                                const float* __restrict__ b2,
                                                float* __restrict__ qpb) {
    int t = threadIdx.x;
    float s = 0.f;
#pragma unroll 8
    for (int c = 0; c < H; ++c) s = fmaf(q[c], W2[c * H + t], s);
    qpb[t] = s + b1[t] + b2[t];
}

// ---------------- prep 2: pack W1 into bf16 hi/lo MFMA B-fragment order --------------
// Layout (bf16x8-granules): frag(ct 0..15, ks 0..7, h 0..1)[lane 0..63]:
//   element j: W1split[h][k = ks*32 + (lane>>4)*8 + j][n = ct*16 + (lane&15)]
__global__ __launch_bounds__(256) void prep_bpack(const float* __restrict__ W1,
                                                  unsigned short* __restrict__ Bpack) {
    int tid = blockIdx.x * 256 + threadIdx.x;  // 0..8191 = (ct,ks,lane)
    int ct = tid >> 9;
    int ks = (tid >> 6) & 7;
    int l  = tid & 63;
    bf16x8 hi, lo;
#pragma unroll
    for (int j = 0; j < 8; ++j) {
        int kk = ks * 32 + ((l >> 4) & 3) * 8 + j;
        int nn = ct * 16 + (l & 15);
        float w = W1[kk * H + nn];
        unsigned short h = f2bf(w);
        float rem = w - bf2f(h);
        hi[j] = (short)h;
        lo[j] = (short)f2bf(rem);
    }
    bf16x8* out = (bf16x8*)Bpack;
    out[((ct * 8 + ks) * 2 + 0) * 64 + l] = hi;
    out[((ct * 8 + ks) * 2 + 1) * 64 + l] = lo;
}

// ---------------- main: scores[m] = sum_d tanh(k@W1 + qpb)[m,d] * V[d] ----------------
// 512 threads = 8 waves; each wave owns 64 rows x 32 cols (rt=4, ct=2).
// ISA-level pipeline: B prefetched one ks ahead via asm global_load_dwordx4,
// counted s_waitcnt vmcnt(4) (never 0 mid-loop) + sched_barrier(0) fences.
__global__ __launch_bounds__(512, 4) void fused_main(const float* __restrict__ kin,
                                                     const unsigned short* __restrict__ Bpack,
                                                     const float* __restrict__ qpb,
                                                     const float* __restrict__ Vp,
                                                     float* __restrict__ out_scores) {
    // LDS: A_hi [64 rows][256 k] bf16 (32 KB) + A_lo (32 KB), XOR-swizzled
    __shared__ __align__(16) unsigned char lds[65536];
    unsigned char* Ahi = lds;
    unsigned char* Alo = lds + 32768;

    const int t  = threadIdx.x;          // 0..511
    const int m0 = blockIdx.x * BM;

    // ---- stage k tile: f32 -> bf16 hi/lo into LDS (128B global per thread) ----
#pragma unroll
    for (int i = 0; i < 8; ++i) {
        int flat = i * 2048 + t * 4;      // covers [64][256] floats
        int r = flat >> 8;
        int c = flat & 255;
        const float4 v = *(const float4*)(kin + (m0 + r) * H + c);
        unsigned short h0 = f2bf(v.x), h1 = f2bf(v.y), h2 = f2bf(v.z), h3 = f2bf(v.w);
        u16x4 hi = {h0, h1, h2, h3};
        u16x4 lo = {f2bf(v.x - bf2f(h0)), f2bf(v.y - bf2f(h1)),
                    f2bf(v.z - bf2f(h2)), f2bf(v.w - bf2f(h3))};
        int addr = (r * 512 + c * 2) ^ ((r & 7) << 4);
        *(u16x4*)(Ahi + addr) = hi;
        *(u16x4*)(Alo + addr) = lo;
    }
    __syncthreads();   // drains staging vmcnt to 0 -> our manual counts are exact

    const int wave = t >> 6;             // 0..7
    const int lane = t & 63;
    const int lhi  = lane >> 4;          // 0..3
    const int llo  = lane & 15;          // 0..15

    f32x4 acc[4][2];   // [rt][ct]
#pragma unroll
    for (int a = 0; a < 4; ++a)
#pragma unroll
        for (int b = 0; b < 2; ++b) acc[a][b] = (f32x4){0.f, 0.f, 0.f, 0.f};

    // This wave's B base (bytes). offset(ct,ks,h) = ((ct*8+ks)*2+h)*1024 bytes.
    const char* bbase = (const char*)Bpack + (size_t)(wave * 32 * 64 + lane) * 16;

    bf16x8 Bh[2][2], Bl[2][2];   // [buf][ct] double-buffered, pinned by asm
    // ---- prologue: issue B(ks=0) ----
    Bh[0][0] = gload16(bbase + ((0 * 8 + 0) * 2 + 0) * 1024);
    Bl[0][0] = gload16(bbase + ((0 * 8 + 0) * 2 + 1) * 1024);
    Bh[0][1] = gload16(bbase + ((1 * 8 + 0) * 2 + 0) * 1024);
    Bl[0][1] = gload16(bbase + ((1 * 8 + 0) * 2 + 1) * 1024);

#pragma unroll
    for (int ks = 0; ks < 8; ++ks) {
        const int cur = ks & 1;
        const int nxt = cur ^ 1;
        // issue next-ks B loads: they stay in flight across this ks's MFMAs
        if (ks < 7) {
            Bh[nxt][0] = gload16(bbase + ((0 * 8 + ks + 1) * 2 + 0) * 1024);
            Bl[nxt][0] = gload16(bbase + ((0 * 8 + ks + 1) * 2 + 1) * 1024);
            Bh[nxt][1] = gload16(bbase + ((1 * 8 + ks + 1) * 2 + 0) * 1024);
            Bl[nxt][1] = gload16(bbase + ((1 * 8 + ks + 1) * 2 + 1) * 1024);
        }
        // A fragments for current ks (plain ds_read_b128; compiler emits
        // fine-grained lgkmcnt before consuming MFMAs)
        bf16x8 ah[4], al[4];
#pragma unroll
        for (int rt = 0; rt < 4; ++rt) {
            int r = rt * 16 + llo;
            int byte = (r * 512 + ks * 64 + lhi * 16) ^ ((r & 7) << 4);
            ah[rt] = *(const bf16x8*)(Ahi + byte);
            al[rt] = *(const bf16x8*)(Alo + byte);
        }
        // wait for CURRENT B only (keep next-ks 4 loads in flight); fence so
        // the compiler cannot hoist MFMAs above the wait (rule #18)
        if (ks < 7) { asm volatile("s_waitcnt vmcnt(4)"); }
        else        { asm volatile("s_waitcnt vmcnt(0)"); }
        __builtin_amdgcn_sched_barrier(0);

#pragma unroll
        for (int rt = 0; rt < 4; ++rt)
#pragma unroll
            for (int ct = 0; ct < 2; ++ct) {
                acc[rt][ct] = __builtin_amdgcn_mfma_f32_16x16x32_bf16(ah[rt], Bh[cur][ct], acc[rt][ct], 0, 0, 0);
                acc[rt][ct] = __builtin_amdgcn_mfma_f32_16x16x32_bf16(ah[rt], Bl[cur][ct], acc[rt][ct], 0, 0, 0);
                acc[rt][ct] = __builtin_amdgcn_mfma_f32_16x16x32_bf16(al[rt], Bh[cur][ct], acc[rt][ct], 0, 0, 0);
            }
    }

    // ---- epilogue: tanh, *V, reduce over this wave's 32 cols ----
    float s[4][4];
#pragma unroll
    for (int a = 0; a < 4; ++a)
#pragma unroll
        for (int b = 0; b < 4; ++b) s[a][b] = 0.f;

#pragma unroll
    for (int ct = 0; ct < 2; ++ct) {
        int n = wave * 32 + ct * 16 + llo;   // global col (C-frag col = lane&15)
        float qv = qpb[n];
        float vv = Vp[n];
#pragma unroll
        for (int rt = 0; rt < 4; ++rt)
#pragma unroll
            for (int i = 0; i < 4; ++i) {
                float x = acc[rt][ct][i] + qv;
                float e = __expf(2.f * x);
                float th = 1.f - 2.f * __builtin_amdgcn_rcpf(e + 1.f);
                s[rt][i] += th * vv;
            }
    }
    // reduce across the 16 column-lanes of each group
#pragma unroll
    for (int rt = 0; rt < 4; ++rt)
#pragma unroll
        for (int i = 0; i < 4; ++i) {
            float r = s[rt][i];
#pragma unroll
            for (int mask = 1; mask < 16; mask <<= 1) r += __shfl_xor(r, mask, 16);
            s[rt][i] = r;   // sum over this wave's 32 cols, row rt*16+lhi*4+i
        }

    __syncthreads();                 // done with A region; reuse as partial buffer
    float* part = (float*)lds;       // [8 waves][64 rows]
    if (llo == 0) {
#pragma unroll
        for (int rt = 0; rt < 4; ++rt)
#pragma unroll
            for (int i = 0; i < 4; ++i)
                part[wave * 64 + rt * 16 + lhi * 4 + i] = s[rt][i];
    }
    __syncthreads();
    if (t < BM) {
        float r = 0.f;
#pragma unroll
        for (int w = 0; w < 8; ++w) r += part[w * 64 + t];
        out_scores[m0 + t] = r;
    }
}

// ---------------- softmax over seq axis, in-place on d_out ----------------
__global__ __launch_bounds__(256) void softmax_kernel(float* __restrict__ out) {
    const int b = blockIdx.x;
    const int t = threadIdx.x;
    float* row = out + b * SEQ;
    float v[8];
#pragma unroll
    for (int j = 0; j < 8; ++j) v[j] = row[t + j * 256];
    float mx = v[0];
#pragma unroll
    for (int j = 1; j < 8; ++j) mx = fmaxf(mx, v[j]);
#pragma unroll
    for (int off = 1; off < 64; off <<= 1) mx = fmaxf(mx, __shfl_xor(mx, off, 64));
    __shared__ float redm[4], reds[4];
    int lane = t & 63, w = t >> 6;
    if (lane == 0) redm[w] = mx;
    __syncthreads();
    mx = fmaxf(fmaxf(redm[0], redm[1]), fmaxf(redm[2], redm[3]));
    float e[8], sum = 0.f;
#pragma unroll
    for (int j = 0; j < 8; ++j) { e[j] = __expf(v[j] - mx); sum += e[j]; }
#pragma unroll
    for (int off = 1; off < 64; off <<= 1) sum += __shfl_xor(sum, off, 64);
    if (lane == 0) reds[w] = sum;
    __syncthreads();
    float inv = 1.0f / (reds[0] + reds[1] + reds[2] + reds[3]);
#pragma unroll
    for (int j = 0; j < 8; ++j) row[t + j * 256] = e[j] * inv;
}

extern "C" void kernel_launch(void* const* d_in, const int* in_sizes, int n_in,
                              void* d_out, int out_size, void* d_ws, size_t ws_size,
                              hipStream_t stream) {
    const float* q  = (const float*)d_in[0];
    const float* k  = (const float*)d_in[1];
    const float* W1 = (const float*)d_in[2];
    const float* b1 = (const float*)d_in[3];
    const float* W2 = (const float*)d_in[4];
    const float* b2 = (const float*)d_in[5];
    const float* V  = (const float*)d_in[6];
    // d_in[7] = bv: scalar added to every score -> softmax-invariant, skipped.
    float* out = (float*)d_out;

    float* qpb = (float*)d_ws;                                     // 1 KB
    unsigned short* Bpack = (unsigned short*)((char*)d_ws + 1024); // 256 KB

    prep_qpb<<<1, 256, 0, stream>>>(q, W2, b1, b2, qpb);
    prep_bpack<<<32, 256, 0, stream>>>(W1, Bpack);
    fused_main<<<M_TOTAL / BM, 512, 0, stream>>>(k, Bpack, qpb, V, out);
    softmax_kernel<<<NBATCH, 256, 0, stream>>>(out);
}

// Round 5
// 75.244 us; speedup vs baseline: 1.0498x; 1.0302x over previous
//
#include <hip/hip_runtime.h>

#define H 256
#define SEQ 2048
#define NBATCH 64
#define M_TOTAL (NBATCH * SEQ)   // 131072 rows
#define BM 64                    // rows per block

using bf16x8 = __attribute__((ext_vector_type(8))) short;
using u16x4  = __attribute__((ext_vector_type(4))) unsigned short;
using f32x4  = __attribute__((ext_vector_type(4))) float;

__device__ __forceinline__ unsigned short f2bf(float x) {
    union { float f; unsigned u; } v; v.f = x;
    unsigned r = v.u + 0x7fffu + ((v.u >> 16) & 1u);   // RNE
    return (unsigned short)(r >> 16);
}
__device__ __forceinline__ float bf2f(unsigned short b) {
    union { unsigned u; float f; } v; v.u = ((unsigned)b) << 16;
    return v.f;
}
__device__ __forceinline__ float asf(unsigned u) { union { unsigned u; float f; } v; v.u = u; return v.f; }
__device__ __forceinline__ unsigned asu(float f) { union { float f; unsigned u; } v; v.f = f; return v.u; }

// Raw 16B global load pinned in registers: compiler cannot sink/collapse this.
__device__ __forceinline__ bf16x8 gload16(const void* p) {
    bf16x8 r;
    asm volatile("global_load_dwordx4 %0, %1, off" : "=v"(r) : "v"(p));
    return r;
}

// ---------------- prep 1: qpb[d] = sum_c q[c]*W2[c,d] + b1[d] + b2[d] ----------------
__global__ __launch_bounds__(256) void prep_qpb(const float* __restrict__ q,
                                                const float* __restrict__ W2,
                                                const float* __restrict__ b1,
                                                const float* __restrict__ b2,
                                                float* __restrict__ qpb) {
    int t = threadIdx.x;
    float s = 0.f;
#pragma unroll 8
    for (int c = 0; c < H; ++c) s = fmaf(q[c], W2[c * H + t], s);
    qpb[t] = s + b1[t] + b2[t];
}

// ---------------- prep 2: pack W1 into bf16 hi/lo MFMA fragment order --------------
// Layout (bf16x8-granules): frag(ct 0..15, ks 0..7, h 0..1)[lane 0..63]:
//   element j: W1split[h][k = ks*32 + (lane>>4)*8 + j][n = ct*16 + (lane&15)]
// (A and B fragment lane->(index,k) maps are identical for 16x16x32; this pack
//  is used as the A operand now, indexed by M-row = n.)
__global__ __launch_bounds__(256) void prep_bpack(const float* __restrict__ W1,
                                                  unsigned short* __restrict__ Bpack) {
    int tid = blockIdx.x * 256 + threadIdx.x;  // 0..8191 = (ct,ks,lane)
    int ct = tid >> 9;
    int ks = (tid >> 6) & 7;
    int l  = tid & 63;
    bf16x8 hi, lo;
#pragma unroll
    for (int j = 0; j < 8; ++j) {
        int kk = ks * 32 + ((l >> 4) & 3) * 8 + j;
        int nn = ct * 16 + (l & 15);
        float w = W1[kk * H + nn];
        unsigned short h = f2bf(w);
        float rem = w - bf2f(h);
        hi[j] = (short)h;
        lo[j] = (short)f2bf(rem);
    }
    bf16x8* out = (bf16x8*)Bpack;
    out[((ct * 8 + ks) * 2 + 0) * 64 + l] = hi;
    out[((ct * 8 + ks) * 2 + 1) * 64 + l] = lo;
}

// ---------------- main: scores[m] = sum_n tanh(k@W1 + qpb)[m,n] * V[n] ----------------
// OPERAND-SWAPPED GEMM: C'[n,m] = sum_k W1[k,n]*ktile[m,k]; A = W1 frags (L2->reg,
// ring-prefetched depth-2, counted vmcnt), B = k frags (LDS). 8 waves = 4 n-groups
// x 2 m-groups; wave owns 64 n x 32 m. Epilogue V-dot is in-lane over n + 2 shuffles.
__global__ __launch_bounds__(512, 4) void fused_main(const float* __restrict__ kin,
                                                     const unsigned short* __restrict__ Bpack,
                                                     const float* __restrict__ qpb,
                                                     const float* __restrict__ Vp,
                                                     float* __restrict__ out_scores) {
    // LDS: k_hi [64 m][256 k] bf16 (32 KB) + k_lo (32 KB), XOR-swizzled
    __shared__ __align__(16) unsigned char lds[65536];
    unsigned char* Khi = lds;
    unsigned char* Klo = lds + 32768;

    const int t  = threadIdx.x;          // 0..511
    const int m0 = blockIdx.x * BM;

    // ---- stage k tile: f32 -> bf16 hi/lo via TRUNCATION split (residual carries
    // the truncation error; |k - hi - lo| <= 2^-16 |k|) ----
#pragma unroll
    for (int i = 0; i < 8; ++i) {
        int flat = i * 2048 + t * 4;      // covers [64][256] floats
        int r = flat >> 8;
        int c = flat & 255;
        const float4 v = *(const float4*)(kin + (m0 + r) * H + c);
        unsigned ux = asu(v.x), uy = asu(v.y), uz = asu(v.z), uw = asu(v.w);
        u16x4 hi = {(unsigned short)(ux >> 16), (unsigned short)(uy >> 16),
                    (unsigned short)(uz >> 16), (unsigned short)(uw >> 16)};
        u16x4 lo = {(unsigned short)(asu(v.x - asf(ux & 0xffff0000u)) >> 16),
                    (unsigned short)(asu(v.y - asf(uy & 0xffff0000u)) >> 16),
                    (unsigned short)(asu(v.z - asf(uz & 0xffff0000u)) >> 16),
                    (unsigned short)(asu(v.w - asf(uw & 0xffff0000u)) >> 16)};
        int addr = (r * 512 + c * 2) ^ ((r & 7) << 4);
        *(u16x4*)(Khi + addr) = hi;
        *(u16x4*)(Klo + addr) = lo;
    }
    __syncthreads();

    const int wave = t >> 6;             // 0..7
    const int lane = t & 63;
    const int lhi  = lane >> 4;          // 0..3
    const int llo  = lane & 15;          // 0..15
    const int wn   = wave >> 1;          // 0..3: n-group (64 cols of W1)
    const int wm   = wave & 1;           // 0..1: m-group (32 rows of k)

    f32x4 acc[4][2];   // [nt][mt]
#pragma unroll
    for (int a = 0; a < 4; ++a)
#pragma unroll
        for (int b = 0; b < 2; ++b) acc[a][b] = (f32x4){0.f, 0.f, 0.f, 0.f};

    // W1 frag byte offset for (nt, ks, h): (((wn*4+nt)*8+ks)*2+h)*1024 + lane*16
    const char* bbase = (const char*)Bpack + (size_t)lane * 16;

    bf16x8 w1[3][4];   // ring [slot][ntn*2 + h]; half Hh: ks=Hh>>1, nt=(Hh&1)*2+ntn
    bf16x8 kf[4];      // [mt*2 + h] for current ks

#define ISSUE_HALF(Hh, S)                                                          \
    do {                                                                           \
        const int ks_ = (Hh) >> 1, n0_ = ((Hh) & 1) * 2;                           \
        w1[S][0] = gload16(bbase + (((wn * 4 + n0_    ) * 8 + ks_) * 2 + 0) * 1024);\
        w1[S][1] = gload16(bbase + (((wn * 4 + n0_    ) * 8 + ks_) * 2 + 1) * 1024);\
        w1[S][2] = gload16(bbase + (((wn * 4 + n0_ + 1) * 8 + ks_) * 2 + 0) * 1024);\
        w1[S][3] = gload16(bbase + (((wn * 4 + n0_ + 1) * 8 + ks_) * 2 + 1) * 1024);\
    } while (0)

    // prologue: two halves in flight
    ISSUE_HALF(0, 0);
    ISSUE_HALF(1, 1);

#pragma unroll
    for (int Hh = 0; Hh < 16; ++Hh) {
        if ((Hh & 1) == 0) {
            // k-tile B-fragments for this ks (shared by both halves)
            const int ks = Hh >> 1;
#pragma unroll
            for (int mt = 0; mt < 2; ++mt) {
                int ml = wm * 32 + mt * 16 + llo;
                int byte = (ml * 512 + ks * 64 + lhi * 16) ^ ((ml & 7) << 4);
                kf[mt * 2 + 0] = *(const bf16x8*)(Khi + byte);
                kf[mt * 2 + 1] = *(const bf16x8*)(Klo + byte);
            }
        }
        if (Hh + 2 <= 15) ISSUE_HALF(Hh + 2, (Hh + 2) % 3);
        // wait for half Hh's 4 loads only; keep later halves in flight
        if (Hh <= 13)      { asm volatile("s_waitcnt vmcnt(8)"); }
        else if (Hh == 14) { asm volatile("s_waitcnt vmcnt(4)"); }
        else               { asm volatile("s_waitcnt vmcnt(0)"); }
        __builtin_amdgcn_sched_barrier(0);

        const int slot = Hh % 3;
#pragma unroll
        for (int ntn = 0; ntn < 2; ++ntn) {
            const int nt = (Hh & 1) * 2 + ntn;
#pragma unroll
            for (int mt = 0; mt < 2; ++mt) {
                acc[nt][mt] = __builtin_amdgcn_mfma_f32_16x16x32_bf16(w1[slot][ntn * 2 + 0], kf[mt * 2 + 0], acc[nt][mt], 0, 0, 0);
                acc[nt][mt] = __builtin_amdgcn_mfma_f32_16x16x32_bf16(w1[slot][ntn * 2 + 1], kf[mt * 2 + 0], acc[nt][mt], 0, 0, 0);
                acc[nt][mt] = __builtin_amdgcn_mfma_f32_16x16x32_bf16(w1[slot][ntn * 2 + 0], kf[mt * 2 + 1], acc[nt][mt], 0, 0, 0);
            }
        }
    }
#undef ISSUE_HALF

    // ---- epilogue: tanh, *V, in-lane reduce over this wave's 64 n ----
    // C' layout: m = mt*16 + (lane&15) [+wm*32], n = wn*64 + nt*16 + lhi*4 + i
    f32x4 qv[4], vv[4];
#pragma unroll
    for (int nt = 0; nt < 4; ++nt) {
        qv[nt] = *(const f32x4*)(qpb + wn * 64 + nt * 16 + lhi * 4);
        vv[nt] = *(const f32x4*)(Vp  + wn * 64 + nt * 16 + lhi * 4);
    }
    float sm[2] = {0.f, 0.f};
#pragma unroll
    for (int nt = 0; nt < 4; ++nt)
#pragma unroll
        for (int mt = 0; mt < 2; ++mt)
#pragma unroll
            for (int i = 0; i < 4; ++i) {
                float x = acc[nt][mt][i] + qv[nt][i];
                float e = __expf(2.f * x);
                float th = 1.f - 2.f * __builtin_amdgcn_rcpf(e + 1.f);
                sm[mt] += th * vv[nt][i];
            }
    // sum across the 4 lhi groups (lanes l, l^16, l^32, l^48)
#pragma unroll
    for (int mt = 0; mt < 2; ++mt) {
        sm[mt] += __shfl_xor(sm[mt], 16, 64);
        sm[mt] += __shfl_xor(sm[mt], 32, 64);
    }

    __syncthreads();                 // done with k region; reuse as partial buffer
    float* part = (float*)lds;       // [4 wn][64 m]
    if (lane < 16) {
        part[wn * 64 + wm * 32 +  0 + lane] = sm[0];
        part[wn * 64 + wm * 32 + 16 + lane] = sm[1];
    }
    __syncthreads();
    if (t < BM)
        out_scores[m0 + t] = part[t] + part[64 + t] + part[128 + t] + part[192 + t];
}

// ---------------- softmax over seq axis, in-place on d_out ----------------
__global__ __launch_bounds__(256) void softmax_kernel(float* __restrict__ out) {
    const int b = blockIdx.x;
    const int t = threadIdx.x;
    float* row = out + b * SEQ;
    float v[8];
#pragma unroll
    for (int j = 0; j < 8; ++j) v[j] = row[t + j * 256];
    float mx = v[0];
#pragma unroll
    for (int j = 1; j < 8; ++j) mx = fmaxf(mx, v[j]);
#pragma unroll
    for (int off = 1; off < 64; off <<= 1) mx = fmaxf(mx, __shfl_xor(mx, off, 64));
    __shared__ float redm[4], reds[4];
    int lane = t & 63, w = t >> 6;
    if (lane == 0) redm[w] = mx;
    __syncthreads();
    mx = fmaxf(fmaxf(redm[0], redm[1]), fmaxf(redm[2], redm[3]));
    float e[8], sum = 0.f;
#pragma unroll
    for (int j = 0; j < 8; ++j) { e[j] = __expf(v[j] - mx); sum += e[j]; }
#pragma unroll
    for (int off = 1; off < 64; off <<= 1) sum += __shfl_xor(sum, off, 64);
    if (lane == 0) reds[w] = sum;
    __syncthreads();
    float inv = 1.0f / (reds[0] + reds[1] + reds[2] + reds[3]);
#pragma unroll
    for (int j = 0; j < 8; ++j) row[t + j * 256] = e[j] * inv;
}

extern "C" void kernel_launch(void* const* d_in, const int* in_sizes, int n_in,
                              void* d_out, int out_size, void* d_ws, size_t ws_size,
                              hipStream_t stream) {
    const float* q  = (const float*)d_in[0];
    const float* k  = (const float*)d_in[1];
    const float* W1 = (const float*)d_in[2];
    const float* b1 = (const float*)d_in[3];
    const float* W2 = (const float*)d_in[4];
    const float* b2 = (const float*)d_in[5];
    const float* V  = (const float*)d_in[6];
    // d_in[7] = bv: scalar added to every score -> softmax-invariant, skipped.
    float* out = (float*)d_out;

    float* qpb = (float*)d_ws;                                     // 1 KB
    unsigned short* Bpack = (unsigned short*)((char*)d_ws + 1024); // 256 KB

    prep_qpb<<<1, 256, 0, stream>>>(q, W2, b1, b2, qpb);
    prep_bpack<<<32, 256, 0, stream>>>(W1, Bpack);
    fused_main<<<M_TOTAL / BM, 512, 0, stream>>>(k, Bpack, qpb, V, out);
    softmax_kernel<<<NBATCH, 256, 0, stream>>>(out);
}